// Round 8
// baseline (220.487 us; speedup 1.0000x reference)
//
#include <hip/hip_runtime.h>
#include <hip/hip_bf16.h>

typedef short short8 __attribute__((ext_vector_type(8)));
typedef float f32x4 __attribute__((ext_vector_type(4)));
typedef float f32x16 __attribute__((ext_vector_type(16)));
typedef __hip_bfloat16 bf16;

#define MFMA(a, b, c) __builtin_amdgcn_mfma_f32_16x16x32_bf16(a, b, c, 0, 0, 0)
#define MFMA32(a, b, c) __builtin_amdgcn_mfma_f32_32x32x16_bf16(a, b, c, 0, 0, 0)
#define EXP2(x) __builtin_amdgcn_exp2f(x)

__device__ __forceinline__ void async16(const void* g, void* l) {
  __builtin_amdgcn_global_load_lds((const __attribute__((address_space(1))) void*)g,
                                   (__attribute__((address_space(3))) void*)l, 16, 0, 0);
}

__device__ __forceinline__ short f2bs(float x) {
  bf16 h = __float2bfloat16(x);
  return __builtin_bit_cast(short, h);
}
__device__ __forceinline__ unsigned pk2(float lo, float hi) {
  return ((unsigned)(unsigned short)f2bs(hi) << 16) | (unsigned)(unsigned short)f2bs(lo);
}

// ---------------------------------------------------------------------------
// Fused prep (inputs are f32 — validated by runtime detection in rounds 2-10;
// round 1's bf16 assumption NaN'd, f32 passed every round since):
//   blocks [0,768)    : transpose Wa (f32->bf16), 64x64 tiles (48 x 16)
//   blocks [768,1024) : transpose Wp                (16 x 16)
//   blocks [1024,3072): convert x -> bf16 (8 elems/thread); first 256 of
//                       these also fill rope[t*32+d] = (cos,sin)(t/1e4^(d/32))
// ---------------------------------------------------------------------------
__launch_bounds__(256)
__global__ void prep(const float* __restrict__ Wa, bf16* __restrict__ WaT,
                     const float* __restrict__ Wp, bf16* __restrict__ WpT,
                     const float* __restrict__ x, bf16* __restrict__ xb,
                     float2* __restrict__ tab) {
  __shared__ __align__(16) short Ts[64 * 72];
  int id = blockIdx.x;
  int tid = threadIdx.x;
  if (id < 1024) {
    const float* src; bf16* dst; int R, Cc, bx, by;
    if (id < 768) { src = Wa; dst = WaT; R = 1024; Cc = 3072; bx = id % 48; by = id / 48; }
    else { int r = id - 768; src = Wp; dst = WpT; R = 1024; Cc = 1024; bx = r & 15; by = r >> 4; }
    int r0 = by * 64, c0 = bx * 64;
#pragma unroll
    for (int c = 0; c < 4; ++c) {
      int g = c * 1024 + tid * 4;
      int rr = g >> 6, cc = g & 63;
      float4 v = *(const float4*)(src + (size_t)(r0 + rr) * Cc + c0 + cc);
      Ts[rr * 72 + cc + 0] = f2bs(v.x);
      Ts[rr * 72 + cc + 1] = f2bs(v.y);
      Ts[rr * 72 + cc + 2] = f2bs(v.z);
      Ts[rr * 72 + cc + 3] = f2bs(v.w);
    }
    __syncthreads();
#pragma unroll
    for (int c = 0; c < 2; ++c) {
      int g = c * 2048 + tid * 8;
      int co = g >> 6, ro = g & 63;
      short8 vv;
#pragma unroll
      for (int jj = 0; jj < 8; ++jj) vv[jj] = Ts[(ro + jj) * 72 + co];
      *(short8*)(dst + (size_t)(c0 + co) * R + r0 + ro) = vv;
    }
  } else {
    int cid = id - 1024;
    int i0 = (cid * 256 + tid) * 8;
    float4 a = *(const float4*)(x + i0);
    float4 b = *(const float4*)(x + i0 + 4);
    short8 o;
    o[0] = f2bs(a.x); o[1] = f2bs(a.y); o[2] = f2bs(a.z); o[3] = f2bs(a.w);
    o[4] = f2bs(b.x); o[5] = f2bs(b.y); o[6] = f2bs(b.z); o[7] = f2bs(b.w);
    *(short8*)((short*)xb + i0) = o;
    if (cid < 256) {
      int idx = cid * 256 + tid;                 // 2048*32 entries
      int t = idx >> 5, d = idx & 31;
      float inv = powf(10000.0f, -(float)d * (1.0f / 32.0f));
      float ang = (float)t * inv;
      tab[idx] = make_float2(cosf(ang), sinf(ang));
    }
  }
}

// ---------------------------------------------------------------------------
// QKV GEMM (m97 structure): C[4096,3072] = xb @ WaT^T, 128x128 tile, BK=32.
// Epilogue: bias (f32) + RoPE + head split; q pre-scaled by 0.125*log2(e);
// V written directly transposed into vt [bh][64][2048].
// ---------------------------------------------------------------------------
__launch_bounds__(256)
__global__ void gemm_qkv(const bf16* __restrict__ A, const bf16* __restrict__ Bt,
                         const float* __restrict__ bias,
                         const float2* __restrict__ rope,
                         bf16* __restrict__ qp, bf16* __restrict__ kp,
                         bf16* __restrict__ vp) {
  const int K = 1024;
  __shared__ __align__(16) short As[128 * 32];
  __shared__ __align__(16) short Bs[128 * 32];
  int tid = threadIdx.x;
  int lane = tid & 63, wave = tid >> 6;
  int l = lane & 15, quad = lane >> 4;
  int wm = wave & 1, wn = wave >> 1;
  int mBase = blockIdx.y * 128, nBase = blockIdx.x * 128;

  f32x4 acc[4][4] = {};

  int r0 = tid >> 2;
  int kk = (tid & 3) * 8;
  const bf16* Ap = A + (size_t)(mBase + r0) * K + kk;
  const bf16* Bp = Bt + (size_t)(nBase + r0) * K + kk;
  short* Asp = As + tid * 8;
  short* Bsp = Bs + tid * 8;

  for (int kb = 0; kb < K / 32; ++kb) {
    __syncthreads();
    async16(Ap, Asp);
    async16(Ap + (size_t)64 * K, Asp + 2048);
    async16(Bp, Bsp);
    async16(Bp + (size_t)64 * K, Bsp + 2048);
    Ap += 32; Bp += 32;
    __syncthreads();
    short8 af[4], bfr[4];
#pragma unroll
    for (int i = 0; i < 4; ++i)
      af[i] = *(const short8*)(As + (wm * 64 + i * 16 + l) * 32 + quad * 8);
#pragma unroll
    for (int j = 0; j < 4; ++j)
      bfr[j] = *(const short8*)(Bs + (wn * 64 + j * 16 + l) * 32 + quad * 8);
#pragma unroll
    for (int i = 0; i < 4; ++i)
#pragma unroll
      for (int j = 0; j < 4; ++j)
        acc[i][j] = MFMA(af[i], bfr[j], acc[i][j]);
  }

  int nsec = nBase + wn * 64;
  float bv[4];
#pragma unroll
  for (int j = 0; j < 4; ++j) bv[j] = bias[nsec + j * 16 + l];

  int sel = nsec >> 10;              // 0=q 1=k 2=v   (wave-uniform)
  int h = (nsec & 1023) >> 6;        // head          (wave-uniform)
  if (sel < 2) {
    bf16* dst = (sel == 0) ? qp : kp;
    float mul = (sel == 0) ? 0.18033688f : 1.0f;   // q: 0.125 * log2(e)
#pragma unroll
    for (int i = 0; i < 4; ++i) {
#pragma unroll
      for (int reg = 0; reg < 4; ++reg) {
        int m = mBase + wm * 64 + i * 16 + quad * 4 + reg;
        int t = m & 2047, b = m >> 11;
        size_t base = ((size_t)((b * 16 + h) * 2048 + t)) * 64;
#pragma unroll
        for (int j = 0; j < 2; ++j) {
          int d = j * 16 + l;
          float x1 = acc[i][j][reg] + bv[j];
          float x2 = acc[i][j + 2][reg] + bv[j + 2];
          float2 cs = rope[t * 32 + d];
          dst[base + d]      = __float2bfloat16((x1 * cs.x - x2 * cs.y) * mul);
          dst[base + d + 32] = __float2bfloat16((x2 * cs.x + x1 * cs.y) * mul);
        }
      }
    }
  } else {
    // V: write directly transposed -> vp is vt [bh][d 64][t 2048]
#pragma unroll
    for (int i = 0; i < 4; ++i) {
      int m0 = mBase + wm * 64 + i * 16 + quad * 4;
      int t0 = m0 & 2047, b = m0 >> 11;
#pragma unroll
      for (int j = 0; j < 4; ++j) {
        int d = j * 16 + l;
        uint2 uu;
        uu.x = pk2(acc[i][j][0] + bv[j], acc[i][j][1] + bv[j]);
        uu.y = pk2(acc[i][j][2] + bv[j], acc[i][j][3] + bv[j]);
        *(uint2*)(vp + ((size_t)((b * 16 + h) * 64 + d)) * 2048 + t0) = uu;
      }
    }
  }
}

// ---------------------------------------------------------------------------
// Proj GEMM: out[4096,1024] = yw @ WpT^T + bias, f32 out.
// 64x128 tile (acc 4x2/wave, 4 waves in n) -> grid 8x64 = 512 blocks = 2/CU.
// ---------------------------------------------------------------------------
__launch_bounds__(256)
__global__ void gemm_proj(const bf16* __restrict__ A, const bf16* __restrict__ Bt,
                          const float* __restrict__ bias, float* __restrict__ out) {
  const int K = 1024, Nn = 1024;
  __shared__ __align__(16) short As[64 * 32];
  __shared__ __align__(16) short Bs[128 * 32];
  int tid = threadIdx.x;
  int lane = tid & 63, wave = tid >> 6;
  int l = lane & 15, quad = lane >> 4;
  int mBase = blockIdx.y * 64, nBase = blockIdx.x * 128;

  f32x4 acc[4][2] = {};

  int r0 = tid >> 2;                 // 0..63
  int kk = (tid & 3) * 8;
  const bf16* Ap = A + (size_t)(mBase + r0) * K + kk;
  const bf16* Bp = Bt + (size_t)(nBase + r0) * K + kk;
  short* Asp = As + tid * 8;
  short* Bsp = Bs + tid * 8;

  for (int kb = 0; kb < K / 32; ++kb) {
    __syncthreads();
    async16(Ap, Asp);
    async16(Bp, Bsp);
    async16(Bp + (size_t)64 * K, Bsp + 2048);
    Ap += 32; Bp += 32;
    __syncthreads();
    short8 af[4], bfr[2];
#pragma unroll
    for (int i = 0; i < 4; ++i)
      af[i] = *(const short8*)(As + (i * 16 + l) * 32 + quad * 8);
#pragma unroll
    for (int j = 0; j < 2; ++j)
      bfr[j] = *(const short8*)(Bs + (wave * 32 + j * 16 + l) * 32 + quad * 8);
#pragma unroll
    for (int i = 0; i < 4; ++i)
#pragma unroll
      for (int j = 0; j < 2; ++j)
        acc[i][j] = MFMA(af[i], bfr[j], acc[i][j]);
  }

  int nsec = nBase + wave * 32;
  float bv[2];
#pragma unroll
  for (int j = 0; j < 2; ++j) bv[j] = bias[nsec + j * 16 + l];
#pragma unroll
  for (int i = 0; i < 4; ++i)
#pragma unroll
    for (int reg = 0; reg < 4; ++reg) {
      int m = mBase + i * 16 + quad * 4 + reg;
#pragma unroll
      for (int j = 0; j < 2; ++j)
        out[(size_t)m * Nn + nsec + j * 16 + l] = acc[i][j][reg] + bv[j];
    }
}

// ---------------------------------------------------------------------------
// Flash attention v11: 32x32 swapped-QK^T + fully in-register softmax + PV.
//   v4/v8/v10 post-mortem: three different latency fixes all ~70us because
//   the cost is the per-tile serial chain, dominated by the softmax P LDS
//   round-trip (32 scalar ds_write + reads + waits per tile). v11 removes
//   LDS entirely (T12 recipe adapted to 16-head D=64):
//   - QK^T swapped: sacc = mfma32(K,Q) -> lane holds P[kv=(r&3)+8(r>>2)+4hi]
//     [q=lane&31] (C layout per m74/m101), 16 regs per kv32 tile.
//   - mask+exp2(s-16) in regs (sacc init -16, q pre-scaled by 0.125*log2e).
//   - P -> bf16 pk pairs; partner half exchanged with ONE __shfl_xor(32) per
//     pk word (E/O select trick, derivation in comments below).
//   - PV swapped: accT = mfma32(vt-frag, P^T-frag) -> O^T[d][q]; vt is
//     already [d][t] so A-frags are plain 16B loads. C col = q = lane&31 ->
//     row-sum + normalize are per-lane scalars (one shfl_xor(32) at end).
//   No LDS, no barriers, no P store/load. Grid/work mapping = v4 (32x16,
//   128 q-rows/block, qi-paired for CU balance; wave w: n32 = 4qi+w+1 kv32
//   tiles). 2 waves/SIMD unchanged (reg-capped) but chain ~halved.
// y out: [b][t][h*64+d] bf16
// ---------------------------------------------------------------------------
__launch_bounds__(256)
__global__ void flash_attn(const bf16* __restrict__ q, const bf16* __restrict__ k,
                           const bf16* __restrict__ vt, bf16* __restrict__ y) {
  int tid = threadIdx.x;
  int lane = tid & 63, wave = tid >> 6;
  int l32 = lane & 31, hi = lane >> 5;
  int bh = blockIdx.x;
  int by = blockIdx.y;
  int qi = (by < 8) ? (15 - by) : (by - 8);   // pair long+short across dispatch
  int q0 = qi * 128;
  int bb = bh >> 4, hh = bh & 15;
  int qrb = q0 + wave * 32;                   // this wave's 32 q rows

  const bf16* qh = q + (size_t)bh * 2048 * 64;
  const bf16* kh = k + (size_t)bh * 2048 * 64;
  const bf16* vh = vt + (size_t)bh * 64 * 2048;

  // Q B-frag (col=q=lane&31, k = d16*16 + hi*8 + j): plain 16B loads
  short8 qf[4];
#pragma unroll
  for (int d16 = 0; d16 < 4; ++d16)
    qf[d16] = *(const short8*)(qh + (size_t)(qrb + l32) * 64 + d16 * 16 + hi * 8);

  const bf16* kfp = kh + (size_t)l32 * 64 + hi * 8;    // + (kv0+row)*... row=l32 baked
  const bf16* vfp = vh + (size_t)l32 * 2048 + hi * 8;  // + jd*32*2048 + kv0 + s*16

  f32x16 acc0, acc1;
#pragma unroll
  for (int i = 0; i < 16; ++i) { acc0[i] = 0.f; acc1[i] = 0.f; }
  float lr = 0.f;

  int n32 = (qrb >> 5) + 1;                   // kv32 tiles (last one masked)

  for (int kt = 0; kt < n32; ++kt) {
    int kv0 = kt * 32;

    // K A-frag (row=kv=lane&31, k = d16*16 + hi*8 + j)
    short8 kf[4];
#pragma unroll
    for (int d16 = 0; d16 < 4; ++d16)
      kf[d16] = *(const short8*)(kfp + (size_t)kv0 * 64 + d16 * 16);

    f32x16 sacc;
#pragma unroll
    for (int i = 0; i < 16; ++i) sacc[i] = -16.f;   // exp2(s-16) shift
#pragma unroll
    for (int d16 = 0; d16 < 4; ++d16)
      sacc = MFMA32(kf[d16], qf[d16], sacc);

    // mask (diag tile only; kv0==qrb there) + exp2; p[r] = P[q=l32][kvl(r,hi)]
    float p[16];
    bool diag = (kt == n32 - 1);
#pragma unroll
    for (int r = 0; r < 16; ++r) {
      float s = sacc[r];
      if (diag) {
        int kvl = (r & 3) + 8 * (r >> 2) + 4 * hi;
        s = (kvl <= l32) ? s : -1e30f;
      }
      p[r] = EXP2(s);
    }
    // row-sum partial (this lane's kv subset of row q=l32)
    float ps = 0.f;
#pragma unroll
    for (int r = 0; r < 16; ++r) ps += p[r];
    lr += ps;

    // pack to bf16 pairs: Pk[r2][h] = (p[4r2+2h], p[4r2+2h+1])
    unsigned Pk[4][2];
#pragma unroll
    for (int r2 = 0; r2 < 4; ++r2) {
      Pk[r2][0] = pk2(p[4 * r2 + 0], p[4 * r2 + 1]);
      Pk[r2][1] = pk2(p[4 * r2 + 2], p[4 * r2 + 3]);
    }

    // PV B-frag per kv16-slice s: lane (q,hi) needs P[q][s*16 + hi*8 + j].
    // kvl = s16+hi*8+j decomposes to r2 = 2s+hi, hi'(owner) = j>=4, r03=j&3.
    //   dest lo: w0,w1 = own Pk[2s][*];    w2,w3 = partner Pk[2s][*]
    //   dest hi: w0,w1 = partner Pk[2s+1][*]; w2,w3 = own Pk[2s+1][*]
    // E (exposed to partner) = hi ? Pk[2s] : Pk[2s+1]; pE = shfl_xor(E,32);
    // O (own word)           = hi ? Pk[2s+1] : Pk[2s];
    // w0/w1 = hi ? pE : O ;  w2/w3 = hi ? O : pE.
#pragma unroll
    for (int s = 0; s < 2; ++s) {
      unsigned E0 = hi ? Pk[2 * s][0] : Pk[2 * s + 1][0];
      unsigned E1 = hi ? Pk[2 * s][1] : Pk[2 * s + 1][1];
      unsigned O0 = hi ? Pk[2 * s + 1][0] : Pk[2 * s][0];
      unsigned O1 = hi ? Pk[2 * s + 1][1] : Pk[2 * s][1];
      unsigned pE0 = (unsigned)__shfl_xor((int)E0, 32, 64);
      unsigned pE1 = (unsigned)__shfl_xor((int)E1, 32, 64);
      int4 wz;
      wz.x = (int)(hi ? pE0 : O0);
      wz.y = (int)(hi ? pE1 : O1);
      wz.z = (int)(hi ? O0 : pE0);
      wz.w = (int)(hi ? O1 : pE1);
      short8 pfrag = __builtin_bit_cast(short8, wz);

      // V^T A-frags (row=d_local=lane&31, k = kv s16+hi*8+j): vt plain loads
      short8 vf0 = *(const short8*)(vfp + kv0 + s * 16);
      short8 vf1 = *(const short8*)(vfp + (size_t)32 * 2048 + kv0 + s * 16);
      acc0 = MFMA32(vf0, pfrag, acc0);     // O^T[d 0..31][q]
      acc1 = MFMA32(vf1, pfrag, acc1);     // O^T[d 32..63][q]
    }
  }

  // finish row sum (partner holds the other kv half of row q=l32)
  lr += __shfl_xor(lr, 32, 64);
  float inv = 1.0f / lr;

  // write y: acc C layout col=q=l32, row=d_loc=(r&3)+8(r>>2)+4hi (+32*jd)
  size_t ybase = ((size_t)(bb * 2048 + qrb + l32)) * 1024 + hh * 64;
#pragma unroll
  for (int r2 = 0; r2 < 4; ++r2) {
    uint2 u0, u1;
    u0.x = pk2(acc0[4 * r2 + 0] * inv, acc0[4 * r2 + 1] * inv);
    u0.y = pk2(acc0[4 * r2 + 2] * inv, acc0[4 * r2 + 3] * inv);
    u1.x = pk2(acc1[4 * r2 + 0] * inv, acc1[4 * r2 + 1] * inv);
    u1.y = pk2(acc1[4 * r2 + 2] * inv, acc1[4 * r2 + 3] * inv);
    *(uint2*)(y + ybase + 8 * r2 + 4 * hi)      = u0;
    *(uint2*)(y + ybase + 32 + 8 * r2 + 4 * hi) = u1;
  }
}

// ---------------------------------------------------------------------------
extern "C" void kernel_launch(void* const* d_in, const int* in_sizes, int n_in,
                              void* d_out, int out_size, void* d_ws, size_t ws_size,
                              hipStream_t stream) {
  const float* x  = (const float*)d_in[0];   // [2,2048,1024] f32
  const float* Wa = (const float*)d_in[1];   // [1024,3072]  f32
  const float* ba = (const float*)d_in[2];   // [3072]       f32
  const float* Wp = (const float*)d_in[3];   // [1024,1024]  f32
  const float* bp = (const float*)d_in[4];   // [1024]       f32

  char* ws = (char*)d_ws;
  bf16*   WaT  = (bf16*)(ws);                          // 3072x1024 bf16 (6291456 B)
  bf16*   WpT  = (bf16*)(ws + 6291456);                // 1024x1024 bf16 (2097152 B)
  float2* rope = (float2*)(ws + 8388608);              // 2048x32   (524288 B)
  bf16*   xb   = (bf16*)(ws + 8913152);                // 4096x1024 bf16
  bf16*   qw   = xb + 4194304;                         // [32][2048][64]
  bf16*   kw   = qw + 4194304;
  bf16*   vtw  = kw + 4194304;                         // [32][64][2048]
  bf16*   yw   = vtw + 4194304;                        // [4096][1024]

  prep<<<3072, 256, 0, stream>>>(Wa, WaT, Wp, WpT, x, xb, rope);
  gemm_qkv<<<dim3(24, 32), 256, 0, stream>>>(xb, WaT, ba, rope, qw, kw, vtw);
  flash_attn<<<dim3(32, 16), 256, 0, stream>>>(qw, kw, vtw, yw);
  gemm_proj<<<dim3(8, 64), 256, 0, stream>>>(yw, WpT, bp, (float*)d_out);
}